// Round 9
// baseline (336.073 us; speedup 1.0000x reference)
//
#include <hip/hip_runtime.h>
#include <hip/hip_bf16.h>

// B=16, S=2048, D=512 attention with sum-pool over queries.
// out[b] = ((sum_q softmax(X M X^T * scale)[q,:]) @ X_b) @ Wv,  M = Wq Wk^T.
// Scores GEMM now MX-fp8 (mfma_scale_f32_16x16x128_f8f6f4, scales=1.0):
// halves staging bytes and cuts K-loop barriers 32->8 (passAE was barrier-bound:
// pure MFMA floor is 27us of its 112us). exp2 scale applied in epilogue (Y
// stored at natural N(0,1) scale, ideal for e4m3).
//
// Experiment log (measured):
//  - bf16 16x16x32 core, BK=32, rotate swizzle: passAE 111us, VGPR 76, occ 30%.
//  - BK=64 bf16: occ 30->21%, 125us. REGRESSED.
//  - 32x32x16 core: 11.5M LDS conflicts, 139us. REGRESSED.
//  - XCD swizzle: FETCH 144->55MB but 147us — passAE not fetch-bound. REGRESSED.
//  - R7/R8 k_t/k_out partial-reduce restructure: +14us vs R5 atomics. REVERTED.

#define S_LEN 2048
#define D_DIM 512
#define BATCH 16

typedef short bf16x8 __attribute__((ext_vector_type(8)));
typedef float f32x4 __attribute__((ext_vector_type(4)));
typedef int i32x8 __attribute__((ext_vector_type(8)));

typedef __attribute__((address_space(3))) void lds_void_t;
typedef const __attribute__((address_space(1))) void gbl_void_t;

// exp2 scale: log2(e)/sqrt(512)
#define KSCL 0.06376281516217733f

__device__ __forceinline__ void async_copy16(const void* g, void* l) {
  __builtin_amdgcn_global_load_lds((gbl_void_t*)g, (lds_void_t*)l, 16, 0, 0);
}

__device__ __forceinline__ unsigned short f2bf(float f) {
  unsigned u = __float_as_uint(f);
  u += 0x7fff + ((u >> 16) & 1);   // RNE
  return (unsigned short)(u >> 16);
}
__device__ __forceinline__ float bf2f(unsigned short h) {
  return __uint_as_float((unsigned)h << 16);
}

// HW OCP e4m3 pack/unpack (gfx950 fp8-conversion-insts)
__device__ __forceinline__ unsigned pack4_fp8(float e0, float e1, float e2, float e3) {
  unsigned dw = (unsigned)__builtin_amdgcn_cvt_pk_fp8_f32(e0, e1, 0, false);
  dw = (unsigned)__builtin_amdgcn_cvt_pk_fp8_f32(e2, e3, (int)dw, true);
  return dw;
}

// ---------------- NT GEMM core (bf16 16x16x32), BK=32 — used by Mt/Y/fallbacks.
__device__ __forceinline__ void gemm_core_nt(
    const unsigned short* __restrict__ A, long lda,
    const unsigned short* __restrict__ B, long ldb,
    int K, unsigned short* As, unsigned short* Bs, f32x4 acc[4][4])
{
  const int tid  = threadIdx.x;
  const int lane = tid & 63;
  const int w    = tid >> 6;
  const int wm   = w >> 1, wn = w & 1;
  const int r16  = lane & 15;
  const int kq   = lane >> 4;

  const int j0 = w * 64 + lane;
  const int j1 = (w + 4) * 64 + lane;
  const int r0 = j0 >> 2, cc0 = (((j0 & 3) - (r0 >> 1)) & 3);
  const int r1 = j1 >> 2, cc1 = (((j1 & 3) - (r1 >> 1)) & 3);

  const long a0 = (long)r0 * lda + cc0 * 8;
  const long a1 = (long)r1 * lda + cc1 * 8;
  const long b0 = (long)r0 * ldb + cc0 * 8;
  const long b1 = (long)r1 * ldb + cc1 * 8;

  int aoff[4], boff[4];
#pragma unroll
  for (int mt = 0; mt < 4; ++mt) {
    const int row = wm * 64 + mt * 16 + r16;
    aoff[mt] = row * 32 + (((row >> 1) + kq) & 3) * 8;
  }
#pragma unroll
  for (int nt = 0; nt < 4; ++nt) {
    const int row = wn * 64 + nt * 16 + r16;
    boff[nt] = row * 32 + (((row >> 1) + kq) & 3) * 8;
  }

  for (int k0 = 0; k0 < K; k0 += 32) {
    __syncthreads();
    async_copy16(A + a0 + k0, (char*)As + (w    ) * 1024);
    async_copy16(A + a1 + k0, (char*)As + (w + 4) * 1024);
    async_copy16(B + b0 + k0, (char*)Bs + (w    ) * 1024);
    async_copy16(B + b1 + k0, (char*)Bs + (w + 4) * 1024);
    __syncthreads();

    bf16x8 af[4], bg[4];
#pragma unroll
    for (int mt = 0; mt < 4; ++mt) af[mt] = *(const bf16x8*)&As[aoff[mt]];
#pragma unroll
    for (int nt = 0; nt < 4; ++nt) bg[nt] = *(const bf16x8*)&Bs[boff[nt]];
#pragma unroll
    for (int mt = 0; mt < 4; ++mt)
#pragma unroll
      for (int nt = 0; nt < 4; ++nt)
        acc[mt][nt] = __builtin_amdgcn_mfma_f32_16x16x32_bf16(af[mt], bg[nt], acc[mt][nt], 0, 0, 0);
  }
}

// ---------------- k_prep: casts (bf16 X, fp8 X, bf16 W) + zeroing in ONE launch
__global__ __launch_bounds__(256) void k_prep(
    const float* __restrict__ X, const float* __restrict__ Wq, const float* __restrict__ Wk,
    unsigned short* __restrict__ Xbf, unsigned* __restrict__ Xf8,
    unsigned short* __restrict__ Wqb, unsigned short* __restrict__ Wkb,
    float* __restrict__ zp, float* __restrict__ out)
{
  const int blk = blockIdx.x;
  if (blk < 16384) {
    int i = (blk * 256 + threadIdx.x) * 4;
    float4 v = *(const float4*)(X + i);
    ushort4 o;
    o.x = f2bf(v.x); o.y = f2bf(v.y); o.z = f2bf(v.z); o.w = f2bf(v.w);
    *(ushort4*)(Xbf + i) = o;
    if (Xf8) Xf8[blk * 256 + threadIdx.x] = pack4_fp8(v.x, v.y, v.z, v.w);
  } else if (blk < 16896) {
    const int b2 = blk - 16384;
    const float* s = (b2 < 256) ? Wq : Wk;
    unsigned short* d = (b2 < 256) ? Wqb : Wkb;
    int i = ((b2 & 255) * 256 + threadIdx.x) * 4;
    float4 v = *(const float4*)(s + i);
    ushort4 o;
    o.x = f2bf(v.x); o.y = f2bf(v.y); o.z = f2bf(v.z); o.w = f2bf(v.w);
    *(ushort4*)(d + i) = o;
  } else {
    int i = (blk - 16896) * 256 + threadIdx.x;
    if (i < 73728) zp[i] = 0.0f;          // lrow + wcol + tvec
    else out[i - 73728] = 0.0f;           // 73728+8192 = 81920 = 320*256
  }
}

// ---------------- k_casty: Ybf (bf16) -> Yf8 (e4m3), coalesced
__global__ __launch_bounds__(256) void k_casty(
    const unsigned short* __restrict__ Ybf, unsigned* __restrict__ Yf8)
{
  const int i = blockIdx.x * 256 + threadIdx.x;
  ushort4 v = *(const ushort4*)(Ybf + (long)i * 4);
  Yf8[i] = pack4_fp8(bf2f(v.x), bf2f(v.y), bf2f(v.z), bf2f(v.w));
}

// ---------------- k_mt: Mt[e,d] = sum_c Wk[e,c] Wq[d,c], 64x64 tiles (no scale)
__global__ __launch_bounds__(256) void k_mt(
    const unsigned short* __restrict__ A, const unsigned short* __restrict__ B,
    unsigned short* __restrict__ C)
{
  __shared__ alignas(16) unsigned short As[64 * 32];
  __shared__ alignas(16) unsigned short Bs[64 * 32];
  f32x4 acc[2][2] = {};
  const int tid = threadIdx.x, lane = tid & 63, w = tid >> 6;
  const int wm = w >> 1, wn = w & 1, r16 = lane & 15, kq = lane >> 4;
  const long a0row = (long)blockIdx.y * 64, b0row = (long)blockIdx.x * 64;

  const int prow = tid >> 2, pslot = tid & 3, pc = (pslot - prow) & 3;
  const long asrc = (a0row + prow) * 512 + pc * 8;
  const long bsrc = (b0row + prow) * 512 + pc * 8;

  int aoff[2], boff[2];
#pragma unroll
  for (int t = 0; t < 2; ++t) {
    const int m = wm * 32 + t * 16 + r16;
    aoff[t] = m * 32 + ((m + kq) & 3) * 8;
    const int n = wn * 32 + t * 16 + r16;
    boff[t] = n * 32 + ((n + kq) & 3) * 8;
  }

  for (int k0 = 0; k0 < 512; k0 += 32) {
    __syncthreads();
    async_copy16(A + asrc + k0, (char*)As + w * 1024);
    async_copy16(B + bsrc + k0, (char*)Bs + w * 1024);
    __syncthreads();
    bf16x8 af[2], bg[2];
#pragma unroll
    for (int t = 0; t < 2; ++t) { af[t] = *(const bf16x8*)&As[aoff[t]]; bg[t] = *(const bf16x8*)&Bs[boff[t]]; }
#pragma unroll
    for (int mt = 0; mt < 2; ++mt)
#pragma unroll
      for (int nt = 0; nt < 2; ++nt)
        acc[mt][nt] = __builtin_amdgcn_mfma_f32_16x16x32_bf16(af[mt], bg[nt], acc[mt][nt], 0, 0, 0);
  }

  const int quad = lane >> 4;
#pragma unroll
  for (int mt = 0; mt < 2; ++mt)
#pragma unroll
    for (int nt = 0; nt < 2; ++nt)
#pragma unroll
      for (int r = 0; r < 4; ++r)
        C[(a0row + wm * 32 + mt * 16 + quad * 4 + r) * 512 + b0row + wn * 32 + nt * 16 + r16]
            = f2bf(acc[mt][nt][r]);
}

// ---------------- Y-GEMM: Y[i,e] = sum_d Xbf[i,d]*Mt[e,d]  (bf16 out, natural scale)
__global__ __launch_bounds__(256) void k_gemm_bf16out(
    const unsigned short* __restrict__ A, long lda,
    const unsigned short* __restrict__ B, long ldb, int K,
    unsigned short* __restrict__ C, long ldc)
{
  __shared__ alignas(16) unsigned short As[128 * 32];
  __shared__ alignas(16) unsigned short Bs[128 * 32];
  f32x4 acc[4][4] = {};
  const long am0 = (long)blockIdx.y * 128;
  const long bn0 = (long)blockIdx.x * 128;
  gemm_core_nt(A + am0 * lda, lda, B + bn0 * ldb, ldb, K, As, Bs, acc);

  const int lane = threadIdx.x & 63;
  const int w = threadIdx.x >> 6, wm = w >> 1, wn = w & 1;
  const long row0 = am0 + wm * 64 + (lane >> 4) * 4;
  const long col0 = bn0 + wn * 64 + (lane & 15);
#pragma unroll
  for (int mt = 0; mt < 4; ++mt)
#pragma unroll
    for (int nt = 0; nt < 4; ++nt)
#pragma unroll
      for (int r = 0; r < 4; ++r)
        C[(row0 + mt * 16 + r) * ldc + col0 + nt * 16] = f2bf(acc[mt][nt][r]);
}

// ---------------- pass A (MX-fp8 core): scores -> exp2 -> row sums + fp8 E
// LDS: A/B tiles 128 rows x 128 B, 8 slots of 16B per row; slot s of row r holds
// chunk (s-r)&7 -> consumer ds_read_b128 lands 2 lanes/bank-group (free).
union SMemF8 {
  struct { unsigned char As[128 * 128]; unsigned char Bs[128 * 128]; } s;  // 32 KB
  unsigned E32[128 * 36];   // [col][r4], stride-36 pad (18 KB)
};

__global__ __launch_bounds__(256) void k_passAE_f8(
    const unsigned* __restrict__ Yf8, const unsigned* __restrict__ Xf8,
    float* __restrict__ lrow, unsigned* __restrict__ E)
{
  __shared__ SMemF8 sm;
  f32x4 acc[4][4] = {};
  const int b = blockIdx.z, qt = blockIdx.y, kt = blockIdx.x;
  const long q0 = (long)qt * 128;
  const long n0 = (long)kt * 128;
  const unsigned char* A = (const unsigned char*)Yf8 + ((long)b * S_LEN + q0) * D_DIM;
  const unsigned char* B = (const unsigned char*)Xf8 + ((long)b * S_LEN + n0) * D_DIM;

  const int tid  = threadIdx.x;
  const int lane = tid & 63;
  const int w    = tid >> 6;
  const int wm   = w >> 1, wn = w & 1;
  const int r16  = lane & 15;
  const int quad = lane >> 4;

  // producer: slot-linear id j (16B units): row=j>>3, slot=j&7, chunk c=(slot-row)&7
  long gsrc[4];
#pragma unroll
  for (int p = 0; p < 4; ++p) {
    const int j = p * 256 + tid;
    const int row = j >> 3, slot = j & 7, c = (slot - row) & 7;
    gsrc[p] = (long)row * 512 + c * 16;
  }

  // consumer: 32B operand = chunks {quad*2, quad*2+1}; slot = (chunk + row)&7
  int aoff[4][2], boff[4][2];
#pragma unroll
  for (int t = 0; t < 4; ++t) {
#pragma unroll
    for (int h = 0; h < 2; ++h) {
      const int m = wm * 64 + t * 16 + r16;
      aoff[t][h] = m * 128 + ((quad * 2 + h + m) & 7) * 16;
      const int n = wn * 64 + t * 16 + r16;
      boff[t][h] = n * 128 + ((quad * 2 + h + n) & 7) * 16;
    }
  }

  for (int k0 = 0; k0 < 512; k0 += 128) {
    __syncthreads();
#pragma unroll
    for (int p = 0; p < 4; ++p) {
      async_copy16(A + gsrc[p] + k0, sm.s.As + (p * 256 + tid - lane) * 16);
      async_copy16(B + gsrc[p] + k0, sm.s.Bs + (p * 256 + tid - lane) * 16);
    }
    __syncthreads();

    i32x8 af[4], bg[4];
#pragma unroll
    for (int t = 0; t < 4; ++t) {
      uint4 lo = *(const uint4*)&sm.s.As[aoff[t][0]];
      uint4 hi = *(const uint4*)&sm.s.As[aoff[t][1]];
      af[t][0] = lo.x; af[t][1] = lo.y; af[t][2] = lo.z; af[t][3] = lo.w;
      af[t][4] = hi.x; af[t][5] = hi.y; af[t][6] = hi.z; af[t][7] = hi.w;
      uint4 blo = *(const uint4*)&sm.s.Bs[boff[t][0]];
      uint4 bhi = *(const uint4*)&sm.s.Bs[boff[t][1]];
      bg[t][0] = blo.x; bg[t][1] = blo.y; bg[t][2] = blo.z; bg[t][3] = blo.w;
      bg[t][4] = bhi.x; bg[t][5] = bhi.y; bg[t][6] = bhi.z; bg[t][7] = bhi.w;
    }
#pragma unroll
    for (int mt = 0; mt < 4; ++mt)
#pragma unroll
      for (int nt = 0; nt < 4; ++nt)
        acc[mt][nt] = __builtin_amdgcn_mfma_scale_f32_16x16x128_f8f6f4(
            af[mt], bg[nt], acc[mt][nt], 0, 0,
            0, 0x7F7F7F7F, 0, 0x7F7F7F7F);
  }

  __syncthreads();   // ds_reads done before LDS reused as E32

#pragma unroll
  for (int mt = 0; mt < 4; ++mt) {
    float rs[4] = {0.f, 0.f, 0.f, 0.f};
#pragma unroll
    for (int nt = 0; nt < 4; ++nt) {
      float ev[4];
#pragma unroll
      for (int r = 0; r < 4; ++r) {
        ev[r] = __builtin_amdgcn_exp2f(acc[mt][nt][r] * KSCL);
        rs[r] += ev[r];
      }
      const int col = wn * 64 + nt * 16 + r16;
      const int r4  = wm * 16 + mt * 4 + quad;
      sm.E32[col * 36 + r4] = pack4_fp8(ev[0], ev[1], ev[2], ev[3]);
    }
#pragma unroll
    for (int r = 0; r < 4; ++r) {
      float s = rs[r];
      s += __shfl_xor(s, 1, 64);
      s += __shfl_xor(s, 2, 64);
      s += __shfl_xor(s, 4, 64);
      s += __shfl_xor(s, 8, 64);
      if (r16 == 0)
        atomicAdd(&lrow[(long)b * S_LEN + q0 + wm * 64 + mt * 16 + quad * 4 + r], s);
    }
  }
  __syncthreads();

  unsigned* Eg = E + (((long)(b * 16 + qt)) * 16 + kt) * 4096;
#pragma unroll
  for (int p = 0; p < 4; ++p) {
    const int n = p * 256 + tid;
    const int col = n >> 3, hj = n & 7;
    uint4 v = *(const uint4*)&sm.E32[col * 36 + hj * 4];
    *(uint4*)(Eg + n * 4) = v;
  }
}

// ---------------- pass A (bf16 fallback): scores -> exp2 -> row sums + fp8 E
union SMemAE {
  struct { unsigned short As[128 * 32]; unsigned short Bs[128 * 32]; } s;
  unsigned E32[128 * 36];
};

__global__ __launch_bounds__(256) void k_passAE(
    const unsigned short* __restrict__ Ybf, const unsigned short* __restrict__ Xbf,
    float* __restrict__ lrow, unsigned* __restrict__ E)
{
  __shared__ SMemAE sm;
  f32x4 acc[4][4] = {};
  const int b = blockIdx.z, qt = blockIdx.y, kt = blockIdx.x;
  const long q0 = (long)qt * 128;
  const long n0 = (long)kt * 128;
  gemm_core_nt(Ybf + ((long)b * S_LEN + q0) * D_DIM, D_DIM,
               Xbf + ((long)b * S_LEN + n0) * D_DIM, D_DIM, D_DIM,
               sm.s.As, sm.s.Bs, acc);

  const int lane = threadIdx.x & 63;
  const int w = threadIdx.x >> 6, wm = w >> 1, wn = w & 1;
  const int r16 = lane & 15, quad = lane >> 4;

  __syncthreads();

#pragma unroll
  for (int mt = 0; mt < 4; ++mt) {
    float rs[4] = {0.f, 0.f, 0.f, 0.f};
#pragma unroll
    for (int nt = 0; nt < 4; ++nt) {
      float ev[4];
#pragma unroll
      for (int r = 0; r < 4; ++r) {
        ev[r] = __builtin_amdgcn_exp2f(acc[mt][nt][r] * KSCL);
        rs[r] += ev[r];
      }
      const int col = wn * 64 + nt * 16 + r16;
      const int r4  = wm * 16 + mt * 4 + quad;
      sm.E32[col * 36 + r4] = pack4_fp8(ev[0], ev[1], ev[2], ev[3]);
    }
#pragma unroll
    for (int r = 0; r < 4; ++r) {
      float s = rs[r];
      s += __shfl_xor(s, 1, 64);
      s += __shfl_xor(s, 2, 64);
      s += __shfl_xor(s, 4, 64);
      s += __shfl_xor(s, 8, 64);
      if (r16 == 0)
        atomicAdd(&lrow[(long)b * S_LEN + q0 + wm * 64 + mt * 16 + quad * 4 + r], s);
    }
  }
  __syncthreads();

  unsigned* Eg = E + (((long)(b * 16 + qt)) * 16 + kt) * 4096;
  const int t = threadIdx.x;
#pragma unroll
  for (int p = 0; p < 4; ++p) {
    const int n = p * 256 + t;
    const int col = n >> 3, hj = n & 7;
    uint4 v = *(const uint4*)&sm.E32[col * 36 + hj * 4];
    *(uint4*)(Eg + n * 4) = v;
  }
}

// ---------------- w[b,k] += sum_q E[b,q,k]/l[b,q]  (tiled-layout, coalesced)
__global__ __launch_bounds__(256) void k_wsum(
    const unsigned* __restrict__ E, const float* __restrict__ lrow,
    float* __restrict__ wcol)
{
  __shared__ float rl[512];
  const int kt = blockIdx.x, qq = blockIdx.y, b = blockIdx.z;
  const int tid = threadIdx.x;
  {
    const float* lp = lrow + (long)b * S_LEN + qq * 512;
    rl[tid]       = 1.0f / lp[tid];
    rl[tid + 256] = 1.0f / lp[tid + 256];
  }
  __syncthreads();
  const int col = tid & 127, qsel = tid >> 7;
  float acc = 0.0f;
#pragma unroll
  for (int qt2 = 0; qt2 < 2; ++qt2) {
    const int qtl = qsel * 2 + qt2;
    const int qt = qq * 4 + qtl;
    const unsigned* Ep = E + (((long)(b * 16 + qt)) * 16 + kt) * 4096 + col * 32;
    const float* rlq = rl + qtl * 128;
#pragma unroll
    for (int j = 0; j < 8; ++j) {
      uint4 v = *(const uint4*)(Ep + j * 4);
      const unsigned dws[4] = {v.x, v.y, v.z, v.w};
#pragma unroll
      for (int i = 0; i < 4; ++i) {
        const unsigned dv = dws[i];
        const float* r = rlq + j * 16 + i * 4;
        acc += __builtin_amdgcn_cvt_f32_fp8((int)dv, 0) * r[0];
        acc += __builtin_amdgcn_cvt_f32_fp8((int)dv, 1) * r[1];
        acc += __builtin_amdgcn_cvt_f32_fp8((int)dv, 2) * r[2];
        acc += __builtin_amdgcn_cvt_f32_fp8((int)dv, 3) * r[3];
      }
    }
  }
  atomicAdd(&wcol[(long)b * S_LEN + kt * 128 + col], acc);
}

// ---------------- t[b,d] = sum_k w[b,k] * X[b,k,d]  (R5-proven version)
__global__ __launch_bounds__(256) void k_t(
    const unsigned short* __restrict__ Xbf, const float* __restrict__ wcol,
    float* __restrict__ tvec)
{
  const int b = blockIdx.z;
  const int d = blockIdx.x * 256 + threadIdx.x;
  const int k0 = blockIdx.y * 64;
  const unsigned short* Xp = Xbf + ((long)b * S_LEN + k0) * D_DIM + d;
  const float* wp = wcol + (long)b * S_LEN + k0;
  float acc = 0.0f;
#pragma unroll 8
  for (int k = 0; k < 64; ++k) acc += wp[k] * bf2f(Xp[(long)k * D_DIM]);
  atomicAdd(&tvec[b * D_DIM + d], acc);
}

// ---------------- out[b,e] += sum_{d chunk} t[b,d] * Wv[d,e]  (R5-proven)
__global__ __launch_bounds__(128) void k_out(
    const float* __restrict__ tvec, const float* __restrict__ Wv, float* __restrict__ out)
{
  __shared__ float tl[128];
  const int b = blockIdx.y;
  const int d0 = blockIdx.z * 128;
  const int e = blockIdx.x * 128 + threadIdx.x;
  tl[threadIdx.x] = tvec[b * D_DIM + d0 + threadIdx.x];
  __syncthreads();
  float acc = 0.0f;
#pragma unroll 8
  for (int d = 0; d < 128; ++d) acc += tl[d] * Wv[(long)(d0 + d) * D_DIM + e];
  atomicAdd(&out[b * D_DIM + e], acc);
}

extern "C" void kernel_launch(void* const* d_in, const int* in_sizes, int n_in,
                              void* d_out, int out_size, void* d_ws, size_t ws_size,
                              hipStream_t stream) {
  const float* X  = (const float*)d_in[0];  // [16,2048,512]
  const float* Wq = (const float*)d_in[1];  // [512,512]
  const float* Wk = (const float*)d_in[2];
  const float* Wv = (const float*)d_in[3];
  float* out = (float*)d_out;               // [16,512]

  char* ws = (char*)d_ws;
  unsigned short* Xbf = (unsigned short*)(ws);              // 32 MB
  unsigned short* Ybf = (unsigned short*)(ws + 33554432);   // 32 MB
  unsigned short* Mt  = (unsigned short*)(ws + 67108864);   // 512 KB
  unsigned short* Wqb = (unsigned short*)(ws + 67633152);   // 512 KB
  unsigned short* Wkb = (unsigned short*)(ws + 68157440);   // 512 KB
  float* lrow = (float*)(ws + 68681728);                    // 128 KB  l[b,q]
  float* wcol = (float*)(ws + 68812800);                    // 128 KB  w[b,k]
  float* tvec = (float*)(ws + 68943872);                    // 32 KB   t[b,d]
  unsigned* E   = (unsigned*)(ws + 69206016);               // 64 MB   fp8 E
  unsigned* Xf8 = (unsigned*)(ws + 136314880);              // 16 MB   fp8 X
  unsigned* Yf8 = (unsigned*)(ws + 153092096);              // 16 MB   fp8 Y (end 169869312)
  const bool bigws  = ws_size >= (size_t)136314880;
  const bool f8path = ws_size >= (size_t)169869312;

  // one launch: cast X (bf16 + fp8), cast Wq/Wk, zero lrow/wcol/tvec + out
  k_prep<<<17216, 256, 0, stream>>>(X, Wq, Wk, Xbf, f8path ? Xf8 : nullptr,
                                    Wqb, Wkb, lrow, out);

  // Mt[e,d] = sum_c Wk[e,c] Wq[d,c]  (natural scale; exp2 scale in epilogues)
  k_mt<<<dim3(8, 8), 256, 0, stream>>>(Wkb, Wqb, Mt);

  // Y[i,e] = sum_d Xbf[i,d] * Mt[e,d]
  k_gemm_bf16out<<<dim3(4, 256), 256, 0, stream>>>(Xbf, 512, Mt, 512, 512, Ybf, 512);

  if (f8path) {
    k_casty<<<16384, 256, 0, stream>>>(Ybf, Yf8);
    k_passAE_f8<<<dim3(16, 16, 16), 256, 0, stream>>>(Yf8, Xf8, lrow, E);
    k_wsum<<<dim3(16, 4, 16), 256, 0, stream>>>(E, lrow, wcol);
  } else if (bigws) {
    k_passAE<<<dim3(16, 16, 16), 256, 0, stream>>>(Ybf, Xbf, lrow, E);
    k_wsum<<<dim3(16, 4, 16), 256, 0, stream>>>(E, lrow, wcol);
  } else {
    // minimal fallback: bf16 passAE needs E; assume harness provides >=131MB ws
    k_passAE<<<dim3(16, 16, 16), 256, 0, stream>>>(Ybf, Xbf, lrow, E);
    k_wsum<<<dim3(16, 4, 16), 256, 0, stream>>>(E, lrow, wcol);
  }

  // t = w @ X (bf16 X), out = t @ Wv (fp32)
  k_t<<<dim3(2, 32, 16), 256, 0, stream>>>(Xbf, wcol, tvec);
  k_out<<<dim3(4, 16, 4), 128, 0, stream>>>(tvec, Wv, out);
}